// Round 5
// baseline (23638.412 us; speedup 1.0000x reference)
//
#include <hip/hip_runtime.h>
#include <math.h>

#define B 64
#define S 512
#define H 512
#define G4 2048  // 4*H gate columns

__device__ __forceinline__ float sigmoidf_(float x) {
    return 1.0f / (1.0f + __expf(-x));
}
__device__ __forceinline__ float tanhf_(float x) {
    // tanh(x) = 2*sigmoid(2x) - 1
    return 2.0f / (1.0f + __expf(-2.0f * x)) - 1.0f;
}

// bf16 <-> f32 via raw bits (avoids __hip_bfloat16 API drift)
__device__ __forceinline__ ushort f2bf(float f) {
    union { float f; unsigned int u; } v; v.f = f;
    unsigned int r = v.u + 0x7FFFu + ((v.u >> 16) & 1u);  // round-nearest-even
    return (ushort)(r >> 16);
}
__device__ __forceinline__ float bf2f(ushort s) {
    union { unsigned int u; float f; } v; v.u = ((unsigned int)s) << 16;
    return v.f;
}

// ---------------------------------------------------------------------------
// Kernel 1: xg[t][g][b] = sum_d emb[tok[b][t]][d] * W_ih[g][d] + (b_ih+b_hh)[g]
// stored bf16. Grid (512 t, 16 gtiles of 128), 256 threads. (unchanged, known-good)
// ---------------------------------------------------------------------------
__global__ __launch_bounds__(256)
void xg_gemm(const int* __restrict__ tokens,
             const float* __restrict__ emb,
             const float* __restrict__ W_ih,
             const float* __restrict__ b_ih,
             const float* __restrict__ b_hh,
             ushort* __restrict__ xg)
{
    const int t      = blockIdx.x;
    const int g_base = blockIdx.y * 128;
    const int tid    = threadIdx.x;

    const int b_ld = tid >> 2;
    const int seg  = tid & 3;
    const int r_w  = tid >> 1;
    const int half = tid & 1;
    const int b0 = (tid & 15) * 4;
    const int g0 = (tid >> 4) * 8;

    const int token = tokens[b_ld * S + t];
    const float4* embrow = reinterpret_cast<const float4*>(emb) + (size_t)token * (H / 4);

    __shared__ float hs[64][64];
    __shared__ float ws[128][68];

    float acc[4][8];
    #pragma unroll
    for (int i = 0; i < 4; ++i)
        #pragma unroll
        for (int j = 0; j < 8; ++j) acc[i][j] = 0.0f;

    for (int kc = 0; kc < 8; ++kc) {
        const int d0 = kc * 64;
        #pragma unroll
        for (int i = 0; i < 4; ++i) {
            const int dl = seg * 16 + i * 4;
            const float4 f = embrow[(d0 >> 2) + seg * 4 + i];
            hs[dl + 0][b_ld] = f.x;
            hs[dl + 1][b_ld] = f.y;
            hs[dl + 2][b_ld] = f.z;
            hs[dl + 3][b_ld] = f.w;
        }
        const float4* wrow = reinterpret_cast<const float4*>(W_ih) +
                             (size_t)(g_base + r_w) * (H / 4) + (d0 >> 2) + half * 8;
        #pragma unroll
        for (int i = 0; i < 8; ++i) {
            *reinterpret_cast<float4*>(&ws[r_w][half * 32 + i * 4]) = wrow[i];
        }
        __syncthreads();

        #pragma unroll
        for (int d4 = 0; d4 < 16; ++d4) {
            const float4 hv0 = *reinterpret_cast<const float4*>(&hs[d4 * 4 + 0][b0]);
            const float4 hv1 = *reinterpret_cast<const float4*>(&hs[d4 * 4 + 1][b0]);
            const float4 hv2 = *reinterpret_cast<const float4*>(&hs[d4 * 4 + 2][b0]);
            const float4 hv3 = *reinterpret_cast<const float4*>(&hs[d4 * 4 + 3][b0]);
            #pragma unroll
            for (int gg = 0; gg < 8; ++gg) {
                const float4 w = *reinterpret_cast<const float4*>(&ws[g0 + gg][d4 * 4]);
                acc[0][gg] += hv0.x * w.x + hv1.x * w.y + hv2.x * w.z + hv3.x * w.w;
                acc[1][gg] += hv0.y * w.x + hv1.y * w.y + hv2.y * w.z + hv3.y * w.w;
                acc[2][gg] += hv0.z * w.x + hv1.z * w.y + hv2.z * w.z + hv3.z * w.w;
                acc[3][gg] += hv0.w * w.x + hv1.w * w.y + hv2.w * w.z + hv3.w * w.w;
            }
        }
        __syncthreads();
    }

    #pragma unroll
    for (int gg = 0; gg < 8; ++gg) {
        const int g = g_base + g0 + gg;
        const float bias = b_ih[g] + b_hh[g];
        ushort4 us;
        us.x = f2bf(acc[0][gg] + bias);
        us.y = f2bf(acc[1][gg] + bias);
        us.z = f2bf(acc[2][gg] + bias);
        us.w = f2bf(acc[3][gg] + bias);
        *reinterpret_cast<ushort4*>(&xg[((size_t)t * G4 + g) * 64 + b0]) = us;
    }
}

// ---------------------------------------------------------------------------
// Kernel 2: persistent LSTM recurrence.
// Grid 256 wgs x 256 thr. 8 groups of 32 wgs; group g = blockIdx&7 owns
// batches [8g,8g+8). wg w = blockIdx>>3 owns hidden k in [16w,16w+16)
// (64 W_hh rows). Thread (rp=tid&31, d8=tid>>5) holds rows {2rp,2rp+1},
// d-slice [64*d8, 64*d8+64) of W_hh in 128 VGPRs (loaded once).
// Per step: stage group h (16KB) -> LDS, 1024 FMAs/thread, LDS partial
// reduce, 128 combine threads (c in registers) produce h_new -> hq ping-pong
// + out. 32-wg flag barrier (threadfence + atomicAdd + acquire spin).
// ---------------------------------------------------------------------------
#define GSTR 4096          // 8 b * 512 d floats per group
#define PSTR 32768         // per parity: 8 groups * GSTR

__global__ __launch_bounds__(256, 1)
void lstm_persist(const float* __restrict__ W_hh,
                  const ushort* __restrict__ xg,
                  float* __restrict__ hq,        // [2][8][8][512]
                  unsigned int* __restrict__ bar, // [8]
                  float* __restrict__ out)
{
    const int tid = threadIdx.x;
    const int g   = blockIdx.x & 7;
    const int w   = blockIdx.x >> 3;
    const int k0  = w * 16;

    const int rp = tid & 31;
    const int d8 = tid >> 5;       // 0..7
    const int d0 = d8 * 64;

    // combine roles (tid < 128)
    const int b8 = tid >> 4;       // 0..7
    const int kl = tid & 15;       // 0..15

    // ---- load W slice into registers (once) ----
    float4 wreg[2][16];
    #pragma unroll
    for (int r = 0; r < 2; ++r) {
        const int rl = 2 * rp + r;                      // 0..63
        const int grow = (rl >> 4) * H + k0 + (rl & 15); // global W_hh row
        const float4* wp = reinterpret_cast<const float4*>(W_hh + (size_t)grow * H + d0);
        #pragma unroll
        for (int i = 0; i < 16; ++i) wreg[r][i] = wp[i];
    }

    __shared__ float hs[8 * 512];        // [b][d] == hq group slice layout
    __shared__ float part[8 * 8 * 64];   // [d8][b][row]

    float c_reg = 0.0f;

    for (int t = 0; t < S; ++t) {
        // ---- stage h_prev (group slice, 16 KB) ----
        const float* hsrc = hq + (t & 1) * PSTR + g * GSTR;
        #pragma unroll
        for (int i = 0; i < 4; ++i)
            reinterpret_cast<float4*>(hs)[i * 256 + tid] =
                reinterpret_cast<const float4*>(hsrc)[i * 256 + tid];
        __syncthreads();

        // ---- prefetch xg for combine (overlaps FMA loop) ----
        float xv[4];
        if (tid < 128) {
            #pragma unroll
            for (int gate = 0; gate < 4; ++gate)
                xv[gate] = bf2f(xg[((size_t)t * G4 + gate * H + k0 + kl) * 64 + g * 8 + b8]);
        }

        // ---- FMA phase: 2 rows x 8 batches x 64 d ----
        float acc[2][8];
        #pragma unroll
        for (int r = 0; r < 2; ++r)
            #pragma unroll
            for (int b = 0; b < 8; ++b) acc[r][b] = 0.0f;

        #pragma unroll
        for (int b = 0; b < 8; ++b) {
            const float4* h4 = reinterpret_cast<const float4*>(hs + b * 512 + d0);
            #pragma unroll
            for (int i = 0; i < 16; ++i) {
                const float4 hv = h4[i];
                acc[0][b] += wreg[0][i].x * hv.x + wreg[0][i].y * hv.y +
                             wreg[0][i].z * hv.z + wreg[0][i].w * hv.w;
                acc[1][b] += wreg[1][i].x * hv.x + wreg[1][i].y * hv.y +
                             wreg[1][i].z * hv.z + wreg[1][i].w * hv.w;
            }
        }

        // ---- partial store [d8][b][row] ----
        #pragma unroll
        for (int r = 0; r < 2; ++r)
            #pragma unroll
            for (int b = 0; b < 8; ++b)
                part[d8 * 512 + b * 64 + 2 * rp + r] = acc[r][b];
        __syncthreads();

        // ---- combine: gates, c update, h_new ----
        if (tid < 128) {
            float v[4];
            #pragma unroll
            for (int gate = 0; gate < 4; ++gate) {
                const int rl = gate * 16 + kl;
                float s = 0.0f;
                #pragma unroll
                for (int q = 0; q < 8; ++q) s += part[q * 512 + b8 * 64 + rl];
                v[gate] = s + xv[gate];
            }
            const float ig = sigmoidf_(v[0]);
            const float fg = sigmoidf_(v[1]);
            const float gg = tanhf_(v[2]);
            const float og = sigmoidf_(v[3]);

            const float cn = fg * c_reg + ig * gg;
            c_reg = cn;
            const float hn = og * tanhf_(cn);

            hq[((t & 1) ^ 1) * PSTR + g * GSTR + b8 * 512 + k0 + kl] = hn;
            out[((size_t)(g * 8 + b8) * S + t) * H + k0 + kl] = hn;
            if (t == S - 1) {
                const size_t OFF = (size_t)B * S * H;
                out[OFF + (size_t)(g * 8 + b8) * H + k0 + kl] = hn;               // final h
                out[OFF + (size_t)B * H + (size_t)(g * 8 + b8) * H + k0 + kl] = cn; // final c
            }
        }

        // ---- group barrier (32 wgs) ----
        __threadfence();       // release h_new to device scope
        __syncthreads();       // all threads' stores+fences done before arrive
        if (tid == 0) {
            atomicAdd(&bar[g], 1u);
            const unsigned int target = 32u * (unsigned int)(t + 1);
            while (__hip_atomic_load(&bar[g], __ATOMIC_ACQUIRE,
                                     __HIP_MEMORY_SCOPE_AGENT) < target)
                __builtin_amdgcn_s_sleep(2);
        }
        __syncthreads();
        __threadfence();       // acquire: invalidate stale h before next stage
    }
}

// ---------------------------------------------------------------------------
// Fallback (round-2 path) if ws_size is too small.
// ---------------------------------------------------------------------------
__global__ __launch_bounds__(128)
void lstm_step_fb(const int* __restrict__ tokens,
                  const float* __restrict__ emb,
                  const float* __restrict__ W_ih,
                  const float* __restrict__ W_hh,
                  const float* __restrict__ b_ih,
                  const float* __restrict__ b_hh,
                  const float* __restrict__ h_prev,
                  float* __restrict__ h_next,
                  float* __restrict__ c_st,
                  float* __restrict__ out,
                  int t)
{
    const int tid = threadIdx.x;
    const int b   = tid & 63;
    const int k   = blockIdx.x * 2 + (tid >> 6);
    const int token = tokens[b * S + t];
    const float* xrow = emb + (size_t)token * H;
    const float* hrow = h_prev + b * H;
    float acc[4];
    #pragma unroll
    for (int g = 0; g < 4; ++g) acc[g] = b_ih[g * H + k] + b_hh[g * H + k];
    for (int d = 0; d < H; ++d) {
        const float xv = xrow[d], hv = hrow[d];
        #pragma unroll
        for (int g = 0; g < 4; ++g)
            acc[g] += xv * W_ih[(size_t)(g * H + k) * H + d] + hv * W_hh[(size_t)(g * H + k) * H + d];
    }
    const float ig = sigmoidf_(acc[0]);
    const float fg = sigmoidf_(acc[1]);
    const float gg = tanhf(acc[2]);
    const float og = sigmoidf_(acc[3]);
    const int ck = b * H + k;
    const float cn = fg * c_st[ck] + ig * gg;
    c_st[ck] = cn;
    const float hn = og * tanhf(cn);
    h_next[ck] = hn;
    out[(size_t)b * S * H + (size_t)t * H + k] = hn;
    if (t == S - 1) {
        out[(size_t)B * S * H + ck] = hn;
        out[(size_t)B * S * H + B * H + ck] = cn;
    }
}

extern "C" void kernel_launch(void* const* d_in, const int* in_sizes, int n_in,
                              void* d_out, int out_size, void* d_ws, size_t ws_size,
                              hipStream_t stream)
{
    const int*   tokens = (const int*)d_in[0];
    const float* emb    = (const float*)d_in[1];
    const float* W_ih   = (const float*)d_in[2];
    const float* W_hh   = (const float*)d_in[3];
    const float* b_ih   = (const float*)d_in[4];
    const float* b_hh   = (const float*)d_in[5];
    float* out = (float*)d_out;

    // ws layout: xg bf16 [S][G4][B] | hq f32 [2][8][8][512] | bar u32 [8] (pad 256B)
    const size_t XG_BYTES  = (size_t)S * G4 * B * 2;       // 134217728
    const size_t HQ_BYTES  = (size_t)2 * PSTR * 4;         // 262144
    const size_t BAR_BYTES = 256;
    const size_t NEED = XG_BYTES + HQ_BYTES + BAR_BYTES;

    if (ws_size >= NEED) {
        ushort* xg = (ushort*)d_ws;
        float*  hq = (float*)((char*)d_ws + XG_BYTES);
        unsigned int* bar = (unsigned int*)((char*)d_ws + XG_BYTES + HQ_BYTES);

        (void)hipMemsetAsync(hq, 0, HQ_BYTES, stream);   // h_0 = 0 (both parities)
        (void)hipMemsetAsync(bar, 0, BAR_BYTES, stream); // barrier counters

        xg_gemm<<<dim3(S, 16), dim3(256), 0, stream>>>(tokens, emb, W_ih, b_ih, b_hh, xg);

        lstm_persist<<<dim3(256), dim3(256), 0, stream>>>(W_hh, xg, hq, bar, out);
    } else {
        // fallback: round-2 correct path (needs 3*B*H floats)
        float* c_st = (float*)d_ws;
        float* h0   = c_st + B * H;
        float* h1   = h0 + B * H;
        (void)hipMemsetAsync(d_ws, 0, (size_t)3 * B * H * sizeof(float), stream);
        for (int t = 0; t < S; ++t) {
            const float* hp = (t & 1) ? h1 : h0;
            float*       hn = (t & 1) ? h0 : h1;
            lstm_step_fb<<<dim3(256), dim3(128), 0, stream>>>(
                tokens, emb, W_ih, W_hh, b_ih, b_hh, hp, hn, c_st, out, t);
        }
    }
}

// Round 6
// 6655.333 us; speedup vs baseline: 3.5518x; 3.5518x over previous
//
#include <hip/hip_runtime.h>
#include <math.h>

#define B 64
#define S 512
#define H 512
#define G4 2048  // 4*H gate columns

__device__ __forceinline__ float sigmoidf_(float x) {
    return 1.0f / (1.0f + __expf(-x));
}
__device__ __forceinline__ float tanhf_(float x) {
    return 2.0f / (1.0f + __expf(-2.0f * x)) - 1.0f;
}

// bf16 <-> f32 via raw bits
__device__ __forceinline__ ushort f2bf(float f) {
    union { float f; unsigned int u; } v; v.f = f;
    unsigned int r = v.u + 0x7FFFu + ((v.u >> 16) & 1u);
    return (ushort)(r >> 16);
}
__device__ __forceinline__ float bf2f(ushort s) {
    union { unsigned int u; float f; } v; v.u = ((unsigned int)s) << 16;
    return v.f;
}

// ---------------------------------------------------------------------------
// Kernel 1: xg[t][g][b] = emb[tok[b][t]] . W_ih[g] + bias[g], bf16. (known-good)
// ---------------------------------------------------------------------------
__global__ __launch_bounds__(256)
void xg_gemm(const int* __restrict__ tokens,
             const float* __restrict__ emb,
             const float* __restrict__ W_ih,
             const float* __restrict__ b_ih,
             const float* __restrict__ b_hh,
             ushort* __restrict__ xg)
{
    const int t      = blockIdx.x;
    const int g_base = blockIdx.y * 128;
    const int tid    = threadIdx.x;

    const int b_ld = tid >> 2;
    const int seg  = tid & 3;
    const int r_w  = tid >> 1;
    const int half = tid & 1;
    const int b0 = (tid & 15) * 4;
    const int g0 = (tid >> 4) * 8;

    const int token = tokens[b_ld * S + t];
    const float4* embrow = reinterpret_cast<const float4*>(emb) + (size_t)token * (H / 4);

    __shared__ float hs[64][64];
    __shared__ float ws[128][68];

    float acc[4][8];
    #pragma unroll
    for (int i = 0; i < 4; ++i)
        #pragma unroll
        for (int j = 0; j < 8; ++j) acc[i][j] = 0.0f;

    for (int kc = 0; kc < 8; ++kc) {
        const int d0 = kc * 64;
        #pragma unroll
        for (int i = 0; i < 4; ++i) {
            const int dl = seg * 16 + i * 4;
            const float4 f = embrow[(d0 >> 2) + seg * 4 + i];
            hs[dl + 0][b_ld] = f.x;
            hs[dl + 1][b_ld] = f.y;
            hs[dl + 2][b_ld] = f.z;
            hs[dl + 3][b_ld] = f.w;
        }
        const float4* wrow = reinterpret_cast<const float4*>(W_ih) +
                             (size_t)(g_base + r_w) * (H / 4) + (d0 >> 2) + half * 8;
        #pragma unroll
        for (int i = 0; i < 8; ++i) {
            *reinterpret_cast<float4*>(&ws[r_w][half * 32 + i * 4]) = wrow[i];
        }
        __syncthreads();

        #pragma unroll
        for (int d4 = 0; d4 < 16; ++d4) {
            const float4 hv0 = *reinterpret_cast<const float4*>(&hs[d4 * 4 + 0][b0]);
            const float4 hv1 = *reinterpret_cast<const float4*>(&hs[d4 * 4 + 1][b0]);
            const float4 hv2 = *reinterpret_cast<const float4*>(&hs[d4 * 4 + 2][b0]);
            const float4 hv3 = *reinterpret_cast<const float4*>(&hs[d4 * 4 + 3][b0]);
            #pragma unroll
            for (int gg = 0; gg < 8; ++gg) {
                const float4 w = *reinterpret_cast<const float4*>(&ws[g0 + gg][d4 * 4]);
                acc[0][gg] += hv0.x * w.x + hv1.x * w.y + hv2.x * w.z + hv3.x * w.w;
                acc[1][gg] += hv0.y * w.x + hv1.y * w.y + hv2.y * w.z + hv3.y * w.w;
                acc[2][gg] += hv0.z * w.x + hv1.z * w.y + hv2.z * w.z + hv3.z * w.w;
                acc[3][gg] += hv0.w * w.x + hv1.w * w.y + hv2.w * w.z + hv3.w * w.w;
            }
        }
        __syncthreads();
    }

    #pragma unroll
    for (int gg = 0; gg < 8; ++gg) {
        const int g = g_base + g0 + gg;
        const float bias = b_ih[g] + b_hh[g];
        ushort4 us;
        us.x = f2bf(acc[0][gg] + bias);
        us.y = f2bf(acc[1][gg] + bias);
        us.z = f2bf(acc[2][gg] + bias);
        us.w = f2bf(acc[3][gg] + bias);
        *reinterpret_cast<ushort4*>(&xg[((size_t)t * G4 + g) * 64 + b0]) = us;
    }
}

// ---------------------------------------------------------------------------
// Kernel 2: persistent LSTM recurrence (R5 skeleton; fences removed, weights
// pinned via waves_per_eu(1,1)).
// 256 wgs x 256 thr, 1 wg/CU. Group g = blockIdx&7 owns batches [8g,8g+8);
// wg w = blockIdx>>3 owns k in [16w,16w+16) (64 W_hh rows). Thread holds
// 2 rows x 64 d of W_hh in 128 VGPRs, loaded once.
// Cross-wg h exchange via RELAXED AGENT-scope atomics (flagged, cache-
// bypassing loads/stores -> coherent at the common point, no L2 flush).
// Barrier: s_waitcnt vmcnt(0) + relaxed agent atomicAdd + relaxed spin.
// ---------------------------------------------------------------------------
#define GSTR 4096          // 8 b * 512 d floats per group
#define PSTR 32768         // per parity: 8 groups * GSTR

__global__ __launch_bounds__(256)
__attribute__((amdgpu_waves_per_eu(1, 1)))
void lstm_persist(const float* __restrict__ W_hh,
                  const ushort* __restrict__ xg,
                  float* __restrict__ hq,         // [2][8][8][512]
                  unsigned int* __restrict__ bar, // [8]
                  float* __restrict__ out)
{
    const int tid = threadIdx.x;
    const int g   = blockIdx.x & 7;
    const int w   = blockIdx.x >> 3;
    const int k0  = w * 16;

    const int rp = tid & 31;
    const int d8 = tid >> 5;       // 0..7
    const int d0 = d8 * 64;

    const int b8 = tid >> 4;       // combine roles (tid < 128)
    const int kl = tid & 15;

    // ---- load W slice into registers (once) ----
    float4 wreg[2][16];
    #pragma unroll
    for (int r = 0; r < 2; ++r) {
        const int rl = 2 * rp + r;
        const int grow = (rl >> 4) * H + k0 + (rl & 15);
        const float4* wp = reinterpret_cast<const float4*>(W_hh + (size_t)grow * H + d0);
        #pragma unroll
        for (int i = 0; i < 16; ++i) wreg[r][i] = wp[i];
    }

    __shared__ float hs[8 * 512];        // [b][d]
    __shared__ float part[8 * 8 * 64];   // [d8][b][row]

    float c_reg = 0.0f;

    for (int t = 0; t < S; ++t) {
        // ---- stage h_prev (group slice, 16 KB) via flagged loads ----
        const float* hsrc = hq + (t & 1) * PSTR + g * GSTR;
        #pragma unroll
        for (int i = 0; i < 16; ++i) {
            hs[i * 256 + tid] = __hip_atomic_load(&hsrc[i * 256 + tid],
                                                  __ATOMIC_RELAXED,
                                                  __HIP_MEMORY_SCOPE_AGENT);
        }
        __syncthreads();

        // ---- xg prefetch for combine ----
        float xv[4];
        if (tid < 128) {
            #pragma unroll
            for (int gate = 0; gate < 4; ++gate)
                xv[gate] = bf2f(xg[((size_t)t * G4 + gate * H + k0 + kl) * 64 + g * 8 + b8]);
        }

        // ---- FMA: 2 rows x 8 batches x 64 d ----
        float acc[2][8];
        #pragma unroll
        for (int r = 0; r < 2; ++r)
            #pragma unroll
            for (int b = 0; b < 8; ++b) acc[r][b] = 0.0f;

        #pragma unroll
        for (int b = 0; b < 8; ++b) {
            const float4* h4 = reinterpret_cast<const float4*>(hs + b * 512 + d0);
            #pragma unroll
            for (int i = 0; i < 16; ++i) {
                const float4 hv = h4[i];
                acc[0][b] += wreg[0][i].x * hv.x + wreg[0][i].y * hv.y +
                             wreg[0][i].z * hv.z + wreg[0][i].w * hv.w;
                acc[1][b] += wreg[1][i].x * hv.x + wreg[1][i].y * hv.y +
                             wreg[1][i].z * hv.z + wreg[1][i].w * hv.w;
            }
        }

        #pragma unroll
        for (int r = 0; r < 2; ++r)
            #pragma unroll
            for (int b = 0; b < 8; ++b)
                part[d8 * 512 + b * 64 + 2 * rp + r] = acc[r][b];
        __syncthreads();

        // ---- combine: gates, c update, h_new ----
        if (tid < 128) {
            float v[4];
            #pragma unroll
            for (int gate = 0; gate < 4; ++gate) {
                const int rl = gate * 16 + kl;
                float s = 0.0f;
                #pragma unroll
                for (int q = 0; q < 8; ++q) s += part[q * 512 + b8 * 64 + rl];
                v[gate] = s + xv[gate];
            }
            const float ig = sigmoidf_(v[0]);
            const float fg = sigmoidf_(v[1]);
            const float gg = tanhf_(v[2]);
            const float og = sigmoidf_(v[3]);

            const float cn = fg * c_reg + ig * gg;
            c_reg = cn;
            const float hn = og * tanhf_(cn);

            // flagged store -> visible agent-wide without fences
            __hip_atomic_store(&hq[((t & 1) ^ 1) * PSTR + g * GSTR + b8 * 512 + k0 + kl],
                               hn, __ATOMIC_RELAXED, __HIP_MEMORY_SCOPE_AGENT);
            out[((size_t)(g * 8 + b8) * S + t) * H + k0 + kl] = hn;
            if (t == S - 1) {
                const size_t OFF = (size_t)B * S * H;
                out[OFF + (size_t)(g * 8 + b8) * H + k0 + kl] = hn;
                out[OFF + (size_t)B * H + (size_t)(g * 8 + b8) * H + k0 + kl] = cn;
            }
        }

        // ---- group barrier (32 wgs), no cache-flushing fences ----
        __syncthreads();                         // all lanes' stores issued
        if (tid == 0) {
            asm volatile("s_waitcnt vmcnt(0)" ::: "memory");
            __hip_atomic_fetch_add(&bar[g], 1u, __ATOMIC_RELAXED,
                                   __HIP_MEMORY_SCOPE_AGENT);
            const unsigned int target = 32u * (unsigned int)(t + 1);
            while (__hip_atomic_load(&bar[g], __ATOMIC_RELAXED,
                                     __HIP_MEMORY_SCOPE_AGENT) < target)
                __builtin_amdgcn_s_sleep(2);
        }
        __syncthreads();
    }
}

// ---------------------------------------------------------------------------
// Fallback (round-2 path) if ws_size is too small.
// ---------------------------------------------------------------------------
__global__ __launch_bounds__(128)
void lstm_step_fb(const int* __restrict__ tokens,
                  const float* __restrict__ emb,
                  const float* __restrict__ W_ih,
                  const float* __restrict__ W_hh,
                  const float* __restrict__ b_ih,
                  const float* __restrict__ b_hh,
                  const float* __restrict__ h_prev,
                  float* __restrict__ h_next,
                  float* __restrict__ c_st,
                  float* __restrict__ out,
                  int t)
{
    const int tid = threadIdx.x;
    const int b   = tid & 63;
    const int k   = blockIdx.x * 2 + (tid >> 6);
    const int token = tokens[b * S + t];
    const float* xrow = emb + (size_t)token * H;
    const float* hrow = h_prev + b * H;
    float acc[4];
    #pragma unroll
    for (int g = 0; g < 4; ++g) acc[g] = b_ih[g * H + k] + b_hh[g * H + k];
    for (int d = 0; d < H; ++d) {
        const float xv = xrow[d], hv = hrow[d];
        #pragma unroll
        for (int g = 0; g < 4; ++g)
            acc[g] += xv * W_ih[(size_t)(g * H + k) * H + d] + hv * W_hh[(size_t)(g * H + k) * H + d];
    }
    const float ig = sigmoidf_(acc[0]);
    const float fg = sigmoidf_(acc[1]);
    const float gg = tanhf(acc[2]);
    const float og = sigmoidf_(acc[3]);
    const int ck = b * H + k;
    const float cn = fg * c_st[ck] + ig * gg;
    c_st[ck] = cn;
    const float hn = og * tanhf(cn);
    h_next[ck] = hn;
    out[(size_t)b * S * H + (size_t)t * H + k] = hn;
    if (t == S - 1) {
        out[(size_t)B * S * H + ck] = hn;
        out[(size_t)B * S * H + B * H + ck] = cn;
    }
}

extern "C" void kernel_launch(void* const* d_in, const int* in_sizes, int n_in,
                              void* d_out, int out_size, void* d_ws, size_t ws_size,
                              hipStream_t stream)
{
    const int*   tokens = (const int*)d_in[0];
    const float* emb    = (const float*)d_in[1];
    const float* W_ih   = (const float*)d_in[2];
    const float* W_hh   = (const float*)d_in[3];
    const float* b_ih   = (const float*)d_in[4];
    const float* b_hh   = (const float*)d_in[5];
    float* out = (float*)d_out;

    const size_t XG_BYTES  = (size_t)S * G4 * B * 2;       // 134217728
    const size_t HQ_BYTES  = (size_t)2 * PSTR * 4;         // 262144
    const size_t BAR_BYTES = 256;
    const size_t NEED = XG_BYTES + HQ_BYTES + BAR_BYTES;

    if (ws_size >= NEED) {
        ushort* xg = (ushort*)d_ws;
        float*  hq = (float*)((char*)d_ws + XG_BYTES);
        unsigned int* bar = (unsigned int*)((char*)d_ws + XG_BYTES + HQ_BYTES);

        (void)hipMemsetAsync(hq, 0, HQ_BYTES, stream);
        (void)hipMemsetAsync(bar, 0, BAR_BYTES, stream);

        xg_gemm<<<dim3(S, 16), dim3(256), 0, stream>>>(tokens, emb, W_ih, b_ih, b_hh, xg);

        lstm_persist<<<dim3(256), dim3(256), 0, stream>>>(W_hh, xg, hq, bar, out);
    } else {
        float* c_st = (float*)d_ws;
        float* h0   = c_st + B * H;
        float* h1   = h0 + B * H;
        (void)hipMemsetAsync(d_ws, 0, (size_t)3 * B * H * sizeof(float), stream);
        for (int t = 0; t < S; ++t) {
            const float* hp = (t & 1) ? h1 : h0;
            float*       hn = (t & 1) ? h0 : h1;
            lstm_step_fb<<<dim3(256), dim3(128), 0, stream>>>(
                tokens, emb, W_ih, W_hh, b_ih, b_hh, hp, hn, c_st, out, t);
        }
    }
}

// Round 7
// 5330.870 us; speedup vs baseline: 4.4343x; 1.2485x over previous
//
#include <hip/hip_runtime.h>
#include <math.h>

#define B 64
#define S 512
#define H 512
#define G4 2048  // 4*H gate columns

__device__ __forceinline__ float sigmoidf_(float x) {
    return 1.0f / (1.0f + __expf(-x));
}
__device__ __forceinline__ float tanhf_(float x) {
    return 2.0f / (1.0f + __expf(-2.0f * x)) - 1.0f;
}

// bf16 <-> f32 via raw bits
__device__ __forceinline__ ushort f2bf(float f) {
    union { float f; unsigned int u; } v; v.f = f;
    unsigned int r = v.u + 0x7FFFu + ((v.u >> 16) & 1u);
    return (ushort)(r >> 16);
}
__device__ __forceinline__ float bf2f(ushort s) {
    union { unsigned int u; float f; } v; v.u = ((unsigned int)s) << 16;
    return v.f;
}

// ---------------------------------------------------------------------------
// Kernel 1: xg = x @ W_ih^T + bias, bf16, stored in persist-friendly layout
//   xg[t][g(8)][w(32)][gate(4)][kl(16)][b8(8)]
// so wg (g,w) of lstm_persist reads ONE contiguous 1 KB block per step.
// Grid (512 t, 16 gtiles of 128 gate-cols), 256 threads.
// ---------------------------------------------------------------------------
__global__ __launch_bounds__(256)
void xg_gemm(const int* __restrict__ tokens,
             const float* __restrict__ emb,
             const float* __restrict__ W_ih,
             const float* __restrict__ b_ih,
             const float* __restrict__ b_hh,
             ushort* __restrict__ xg)
{
    const int t      = blockIdx.x;
    const int g_base = blockIdx.y * 128;
    const int tid    = threadIdx.x;

    const int b_ld = tid >> 2;
    const int seg  = tid & 3;
    const int r_w  = tid >> 1;
    const int half = tid & 1;
    const int b0 = (tid & 15) * 4;      // 4 consecutive batches (within one b8-octet)
    const int g0 = (tid >> 4) * 8;

    const int token = tokens[b_ld * S + t];
    const float4* embrow = reinterpret_cast<const float4*>(emb) + (size_t)token * (H / 4);

    __shared__ float hs[64][64];
    __shared__ float ws[128][68];

    float acc[4][8];
    #pragma unroll
    for (int i = 0; i < 4; ++i)
        #pragma unroll
        for (int j = 0; j < 8; ++j) acc[i][j] = 0.0f;

    for (int kc = 0; kc < 8; ++kc) {
        const int d0 = kc * 64;
        #pragma unroll
        for (int i = 0; i < 4; ++i) {
            const int dl = seg * 16 + i * 4;
            const float4 f = embrow[(d0 >> 2) + seg * 4 + i];
            hs[dl + 0][b_ld] = f.x;
            hs[dl + 1][b_ld] = f.y;
            hs[dl + 2][b_ld] = f.z;
            hs[dl + 3][b_ld] = f.w;
        }
        const float4* wrow = reinterpret_cast<const float4*>(W_ih) +
                             (size_t)(g_base + r_w) * (H / 4) + (d0 >> 2) + half * 8;
        #pragma unroll
        for (int i = 0; i < 8; ++i) {
            *reinterpret_cast<float4*>(&ws[r_w][half * 32 + i * 4]) = wrow[i];
        }
        __syncthreads();

        #pragma unroll
        for (int d4 = 0; d4 < 16; ++d4) {
            const float4 hv0 = *reinterpret_cast<const float4*>(&hs[d4 * 4 + 0][b0]);
            const float4 hv1 = *reinterpret_cast<const float4*>(&hs[d4 * 4 + 1][b0]);
            const float4 hv2 = *reinterpret_cast<const float4*>(&hs[d4 * 4 + 2][b0]);
            const float4 hv3 = *reinterpret_cast<const float4*>(&hs[d4 * 4 + 3][b0]);
            #pragma unroll
            for (int gg = 0; gg < 8; ++gg) {
                const float4 w = *reinterpret_cast<const float4*>(&ws[g0 + gg][d4 * 4]);
                acc[0][gg] += hv0.x * w.x + hv1.x * w.y + hv2.x * w.z + hv3.x * w.w;
                acc[1][gg] += hv0.y * w.x + hv1.y * w.y + hv2.y * w.z + hv3.y * w.w;
                acc[2][gg] += hv0.z * w.x + hv1.z * w.y + hv2.z * w.z + hv3.z * w.w;
                acc[3][gg] += hv0.w * w.x + hv1.w * w.y + hv2.w * w.z + hv3.w * w.w;
            }
        }
        __syncthreads();
    }

    const int grp = b0 >> 3;   // batch group 0..7
    const int b8l = b0 & 7;    // 0 or 4
    #pragma unroll
    for (int gg = 0; gg < 8; ++gg) {
        const int gcol = g_base + g0 + gg;
        const int gate = gcol >> 9;        // 0..3
        const int k    = gcol & 511;
        const int w    = k >> 4;           // 0..31
        const int kl   = k & 15;           // 0..15
        const float bias = b_ih[gcol] + b_hh[gcol];
        ushort4 us;
        us.x = f2bf(acc[0][gg] + bias);
        us.y = f2bf(acc[1][gg] + bias);
        us.z = f2bf(acc[2][gg] + bias);
        us.w = f2bf(acc[3][gg] + bias);
        const size_t idx = ((((size_t)t * 8 + grp) * 32 + w) * 512) +
                           gate * 128 + kl * 8 + b8l;
        *reinterpret_cast<ushort4*>(&xg[idx]) = us;
    }
}

// ---------------------------------------------------------------------------
// Kernel 2: persistent LSTM recurrence.
// 256 wgs x 256 thr, 1 wg/CU (waves_per_eu(1,1)). Group g = blockIdx&7 owns
// batches [8g,8g+8); wg w = blockIdx>>3 owns k in [16w,16w+16) (64 W_hh rows).
// h exchange: relaxed AGENT atomics (no cache-flushing fences).
// Barrier counters padded 256 B apart (one LLC line per group).
// xg for step t+1 prefetched into registers during step t's FMA phase.
// ---------------------------------------------------------------------------
#define GSTR 4096          // 8 b * 512 d floats per group
#define PSTR 32768         // per parity: 8 groups * GSTR

__global__ __launch_bounds__(256)
__attribute__((amdgpu_waves_per_eu(1, 1)))
void lstm_persist(const float* __restrict__ W_hh,
                  const ushort* __restrict__ xg,
                  float* __restrict__ hq,         // [2][8][8][512]
                  unsigned int* __restrict__ bar, // 8 counters, 64-uint stride
                  float* __restrict__ out)
{
    const int tid = threadIdx.x;
    const int g   = blockIdx.x & 7;
    const int w   = blockIdx.x >> 3;
    const int k0  = w * 16;

    const int rp = tid & 31;
    const int d8 = tid >> 5;       // 0..7
    const int d0 = d8 * 64;

    const int b8 = tid >> 4;       // combine roles (tid < 128)
    const int kl = tid & 15;

    unsigned int* bcnt = bar + g * 64;   // 256 B apart

    // wg's contiguous xg slice: [t][g][w][gate*128 + kl*8 + b8]
    const ushort* xg_wg = xg + (((size_t)g * 32 + w) * 512);

    // ---- load W slice into registers (once) ----
    float4 wreg[2][16];
    #pragma unroll
    for (int r = 0; r < 2; ++r) {
        const int rl = 2 * rp + r;
        const int grow = (rl >> 4) * H + k0 + (rl & 15);
        const float4* wp = reinterpret_cast<const float4*>(W_hh + (size_t)grow * H + d0);
        #pragma unroll
        for (int i = 0; i < 16; ++i) wreg[r][i] = wp[i];
    }

    __shared__ float hs[8 * 512];        // [b][d]
    __shared__ float part[8 * 8 * 64];   // [d8][b][row]

    float c_reg = 0.0f;

    // prefetch xg for t=0
    float xv_cur[4] = {0.f, 0.f, 0.f, 0.f};
    if (tid < 128) {
        #pragma unroll
        for (int gate = 0; gate < 4; ++gate)
            xv_cur[gate] = bf2f(xg_wg[gate * 128 + kl * 8 + b8]);
    }

    for (int t = 0; t < S; ++t) {
        // ---- stage h_prev (group slice, 16 KB) via 8-byte flagged loads ----
        const unsigned long long* hsrc8 = reinterpret_cast<const unsigned long long*>(
            hq + (t & 1) * PSTR + g * GSTR);
        #pragma unroll
        for (int i = 0; i < 8; ++i) {
            const unsigned long long v = __hip_atomic_load(&hsrc8[i * 256 + tid],
                                                           __ATOMIC_RELAXED,
                                                           __HIP_MEMORY_SCOPE_AGENT);
            reinterpret_cast<unsigned long long*>(hs)[i * 256 + tid] = v;
        }
        __syncthreads();

        // ---- prefetch xg for t+1 (overlaps FMA; no dependence on h) ----
        float xv_nxt[4] = {0.f, 0.f, 0.f, 0.f};
        if (tid < 128 && t + 1 < S) {
            const ushort* p = xg_wg + (size_t)(t + 1) * (8 * 32 * 512);
            #pragma unroll
            for (int gate = 0; gate < 4; ++gate)
                xv_nxt[gate] = bf2f(p[gate * 128 + kl * 8 + b8]);
        }

        // ---- FMA: 2 rows x 8 batches x 64 d ----
        float acc[2][8];
        #pragma unroll
        for (int r = 0; r < 2; ++r)
            #pragma unroll
            for (int b = 0; b < 8; ++b) acc[r][b] = 0.0f;

        #pragma unroll
        for (int b = 0; b < 8; ++b) {
            const float4* h4 = reinterpret_cast<const float4*>(hs + b * 512 + d0);
            #pragma unroll
            for (int i = 0; i < 16; ++i) {
                const float4 hv = h4[i];
                acc[0][b] += wreg[0][i].x * hv.x + wreg[0][i].y * hv.y +
                             wreg[0][i].z * hv.z + wreg[0][i].w * hv.w;
                acc[1][b] += wreg[1][i].x * hv.x + wreg[1][i].y * hv.y +
                             wreg[1][i].z * hv.z + wreg[1][i].w * hv.w;
            }
        }

        #pragma unroll
        for (int r = 0; r < 2; ++r)
            #pragma unroll
            for (int b = 0; b < 8; ++b)
                part[d8 * 512 + b * 64 + 2 * rp + r] = acc[r][b];
        __syncthreads();

        // ---- combine: gates, c update, h_new ----
        if (tid < 128) {
            float v[4];
            #pragma unroll
            for (int gate = 0; gate < 4; ++gate) {
                const int rl = gate * 16 + kl;
                float s = 0.0f;
                #pragma unroll
                for (int q = 0; q < 8; ++q) s += part[q * 512 + b8 * 64 + rl];
                v[gate] = s + xv_cur[gate];
            }
            const float ig = sigmoidf_(v[0]);
            const float fg = sigmoidf_(v[1]);
            const float gg = tanhf_(v[2]);
            const float og = sigmoidf_(v[3]);

            const float cn = fg * c_reg + ig * gg;
            c_reg = cn;
            const float hn = og * tanhf_(cn);

            __hip_atomic_store(&hq[((t & 1) ^ 1) * PSTR + g * GSTR + b8 * 512 + k0 + kl],
                               hn, __ATOMIC_RELAXED, __HIP_MEMORY_SCOPE_AGENT);
            out[((size_t)(g * 8 + b8) * S + t) * H + k0 + kl] = hn;
            if (t == S - 1) {
                const size_t OFF = (size_t)B * S * H;
                out[OFF + (size_t)(g * 8 + b8) * H + k0 + kl] = hn;
                out[OFF + (size_t)B * H + (size_t)(g * 8 + b8) * H + k0 + kl] = cn;
            }
        }

        // ---- group barrier (32 wgs), padded counter, no cache flushes ----
        __syncthreads();     // drains each wave's vmcnt -> h stores visible
        if (tid == 0) {
            __hip_atomic_fetch_add(bcnt, 1u, __ATOMIC_RELAXED,
                                   __HIP_MEMORY_SCOPE_AGENT);
            const unsigned int target = 32u * (unsigned int)(t + 1);
            while (__hip_atomic_load(bcnt, __ATOMIC_RELAXED,
                                     __HIP_MEMORY_SCOPE_AGENT) < target)
                __builtin_amdgcn_s_sleep(2);
        }
        __syncthreads();

        xv_cur[0] = xv_nxt[0]; xv_cur[1] = xv_nxt[1];
        xv_cur[2] = xv_nxt[2]; xv_cur[3] = xv_nxt[3];
    }
}

// ---------------------------------------------------------------------------
// Fallback (round-2 path) if ws_size is too small.
// ---------------------------------------------------------------------------
__global__ __launch_bounds__(128)
void lstm_step_fb(const int* __restrict__ tokens,
                  const float* __restrict__ emb,
                  const float* __restrict__ W_ih,
                  const float* __restrict__ W_hh,
                  const float* __restrict__ b_ih,
                  const float* __restrict__ b_hh,
                  const float* __restrict__ h_prev,
                  float* __restrict__ h_next,
                  float* __restrict__ c_st,
                  float* __restrict__ out,
                  int t)
{
    const int tid = threadIdx.x;
    const int b   = tid & 63;
    const int k   = blockIdx.x * 2 + (tid >> 6);
    const int token = tokens[b * S + t];
    const float* xrow = emb + (size_t)token * H;
    const float* hrow = h_prev + b * H;
    float acc[4];
    #pragma unroll
    for (int g = 0; g < 4; ++g) acc[g] = b_ih[g * H + k] + b_hh[g * H + k];
    for (int d = 0; d < H; ++d) {
        const float xv = xrow[d], hv = hrow[d];
        #pragma unroll
        for (int g = 0; g < 4; ++g)
            acc[g] += xv * W_ih[(size_t)(g * H + k) * H + d] + hv * W_hh[(size_t)(g * H + k) * H + d];
    }
    const float ig = sigmoidf_(acc[0]);
    const float fg = sigmoidf_(acc[1]);
    const float gg = tanhf(acc[2]);
    const float og = sigmoidf_(acc[3]);
    const int ck = b * H + k;
    const float cn = fg * c_st[ck] + ig * gg;
    c_st[ck] = cn;
    const float hn = og * tanhf(cn);
    h_next[ck] = hn;
    out[(size_t)b * S * H + (size_t)t * H + k] = hn;
    if (t == S - 1) {
        out[(size_t)B * S * H + ck] = hn;
        out[(size_t)B * S * H + B * H + ck] = cn;
    }
}

extern "C" void kernel_launch(void* const* d_in, const int* in_sizes, int n_in,
                              void* d_out, int out_size, void* d_ws, size_t ws_size,
                              hipStream_t stream)
{
    const int*   tokens = (const int*)d_in[0];
    const float* emb    = (const float*)d_in[1];
    const float* W_ih   = (const float*)d_in[2];
    const float* W_hh   = (const float*)d_in[3];
    const float* b_ih   = (const float*)d_in[4];
    const float* b_hh   = (const float*)d_in[5];
    float* out = (float*)d_out;

    const size_t XG_BYTES  = (size_t)S * G4 * B * 2;       // 134217728
    const size_t HQ_BYTES  = (size_t)2 * PSTR * 4;         // 262144
    const size_t BAR_BYTES = 8 * 64 * 4;                   // 8 counters, 256 B apart
    const size_t NEED = XG_BYTES + HQ_BYTES + BAR_BYTES;

    if (ws_size >= NEED) {
        ushort* xg = (ushort*)d_ws;
        float*  hq = (float*)((char*)d_ws + XG_BYTES);
        unsigned int* bar = (unsigned int*)((char*)d_ws + XG_BYTES + HQ_BYTES);

        (void)hipMemsetAsync(hq, 0, HQ_BYTES + BAR_BYTES, stream);

        xg_gemm<<<dim3(S, 16), dim3(256), 0, stream>>>(tokens, emb, W_ih, b_ih, b_hh, xg);

        lstm_persist<<<dim3(256), dim3(256), 0, stream>>>(W_hh, xg, hq, bar, out);
    } else {
        float* c_st = (float*)d_ws;
        float* h0   = c_st + B * H;
        float* h1   = h0 + B * H;
        (void)hipMemsetAsync(d_ws, 0, (size_t)3 * B * H * sizeof(float), stream);
        for (int t = 0; t < S; ++t) {
            const float* hp = (t & 1) ? h1 : h0;
            float*       hn = (t & 1) ? h0 : h1;
            lstm_step_fb<<<dim3(256), dim3(128), 0, stream>>>(
                tokens, emb, W_ih, W_hh, b_ih, b_hh, hp, hn, c_st, out, t);
        }
    }
}